// Round 6
// baseline (17.457 us; speedup 1.0000x reference)
//
#include <hip/hip_runtime.h>

typedef float v2f __attribute__((ext_vector_type(2)));

#define THREADS 512
#define NTILE 16   // centers per block
#define NPAIR 8    // packed center pairs (iso path)
#define NPAIR2 4   // pairs per pass (non-iso fallback, 2 passes)

static __device__ __forceinline__ v2f pk_fma(v2f a, v2f b, v2f c) {
    v2f d;
    asm("v_pk_fma_f32 %0, %1, %2, %3" : "=v"(d) : "v"(a), "v"(b), "v"(c));
    return d;
}
static __device__ __forceinline__ v2f pk_mul(v2f a, v2f b) {
    v2f d;
    asm("v_pk_mul_f32 %0, %1, %2" : "=v"(d) : "v"(a), "v"(b));
    return d;
}

// Schraudolph fast exp2 on the pre-scaled domain: y = bitcast((int)u).
static __device__ __forceinline__ v2f fast_exp_pair(v2f u) {
    v2f r;
    r.x = __int_as_float((int)u.x);
    r.y = __int_as_float((int)u.y);
    return r;
}

#define S_CONST    12102203.161561485f  // 2^23 * log2(e)
#define BIAS_CONST 1064872549.0f        // 127*2^23 - 480667 (mean-centered)

// iso (s0==s1): t = A + D*(x0^2+x1^2) + B*x0 + C*x1  -> 3 pk_fma + acc
template <int NP>
static __device__ __forceinline__ void body_iso(
    float x0, float x1, float mk,
    const v2f* Av, const v2f* Bv, const v2f* Cv, const v2f* Dv, v2f* acc)
{
    const float r2 = __builtin_fmaf(x1, x1, x0 * x0);
    const v2f sr2 = {r2, r2}, sx0 = {x0, x0}, sx1 = {x1, x1}, smk = {mk, mk};
#pragma unroll
    for (int i = 0; i < NP; ++i) {
        v2f t = pk_fma(Dv[i], sr2, Av[i]);
        t = pk_fma(Bv[i], sx0, t);
        t = pk_fma(Cv[i], sx1, t);
        acc[i] = pk_fma(fast_exp_pair(t), smk, acc[i]);
    }
}

// generic: t = A + B*x0 + C*x1 + D*x0^2 + E*x1^2
template <int NP>
static __device__ __forceinline__ void body_gen(
    float x0, float x1, float mk,
    const v2f* Av, const v2f* Bv, const v2f* Cv, const v2f* Dv, const v2f* Ev,
    v2f* acc)
{
    const v2f sx0 = {x0, x0}, sx1 = {x1, x1}, smk = {mk, mk};
    const v2f sq0 = pk_mul(sx0, sx0), sq1 = pk_mul(sx1, sx1);
#pragma unroll
    for (int i = 0; i < NP; ++i) {
        v2f t = pk_fma(Bv[i], sx0, Av[i]);
        t = pk_fma(Cv[i], sx1, t);
        t = pk_fma(Dv[i], sq0, t);
        t = pk_fma(Ev[i], sq1, t);
        acc[i] = pk_fma(fast_exp_pair(t), smk, acc[i]);
    }
}

template <int NP, bool ISO>
static __device__ __forceinline__ void main_loop(
    const float4* B4, const float4* M4, int quads, int tid,
    const v2f* Av, const v2f* Bv, const v2f* Cv, const v2f* Dv, const v2f* Ev,
    v2f* acc)
{
    int q = tid;
    if (q >= quads) return;
    float4 pa = B4[2 * q], pb = B4[2 * q + 1], pm = M4[q];
    while (true) {
        const int qn = q + THREADS;
        const bool vn = qn < quads;
        const int qc = vn ? qn : q;  // clamp: loads always valid, unused on exit
        float4 na = B4[2 * qc], nb = B4[2 * qc + 1], nm = M4[qc];

        if (ISO) {
            body_iso<NP>(pa.x, pa.y, pm.x, Av, Bv, Cv, Dv, acc);
            body_iso<NP>(pa.z, pa.w, pm.y, Av, Bv, Cv, Dv, acc);
            body_iso<NP>(pb.x, pb.y, pm.z, Av, Bv, Cv, Dv, acc);
            body_iso<NP>(pb.z, pb.w, pm.w, Av, Bv, Cv, Dv, acc);
        } else {
            body_gen<NP>(pa.x, pa.y, pm.x, Av, Bv, Cv, Dv, Ev, acc);
            body_gen<NP>(pa.z, pa.w, pm.y, Av, Bv, Cv, Dv, Ev, acc);
            body_gen<NP>(pb.x, pb.y, pm.z, Av, Bv, Cv, Dv, Ev, acc);
            body_gen<NP>(pb.z, pb.w, pm.w, Av, Bv, Cv, Dv, Ev, acc);
        }

        if (!vn) break;
        q = qn; pa = na; pb = nb; pm = nm;
    }
}

__global__ __launch_bounds__(THREADS, 4) void slayer_exp_kernel(
    const float* __restrict__ batch,      // [B,P,2]
    const float* __restrict__ not_dummy,  // [B,P]
    const float* __restrict__ centers,    // [N,2]
    const float* __restrict__ sharpness,  // [N,2]
    float* __restrict__ out,              // [B,N]
    int B, int P, int N, int T)           // T = n-tiles per b
{
    // XCD-locality swizzle: the T blocks sharing one b land on the SAME XCD.
    const int id = blockIdx.x;
    int b, j;
    if ((B & 7) == 0) {
        const int r = id >> 3;
        j = r % T;
        b = (r / T) * 8 + (id & 7);
    } else {
        b = id / T;
        j = id % T;
    }
    const int n0  = j * NTILE;
    const int tid = threadIdx.x;

    // Block-uniform isotropy check (data here: sharpness == 3 everywhere).
    bool iso = true;
#pragma unroll
    for (int i = 0; i < NTILE; ++i) {
        int n = n0 + i; if (n >= N) n = N - 1;
        iso = iso && (sharpness[2 * n] == sharpness[2 * n + 1]);
    }

    v2f acc[NPAIR];
#pragma unroll
    for (int i = 0; i < NPAIR; ++i) acc[i] = (v2f){0.0f, 0.0f};

    const float4* B4 = (const float4*)(batch + (size_t)b * P * 2);
    const float4* M4 = (const float4*)(not_dummy + (size_t)b * P);
    const int quads = P >> 2;

    if (iso) {
        v2f Av[NPAIR], Bv[NPAIR], Cv[NPAIR], Dv[NPAIR];
#pragma unroll
        for (int i = 0; i < NPAIR; ++i) {
#pragma unroll
            for (int h = 0; h < 2; ++h) {
                int n = n0 + 2 * i + h; if (n >= N) n = N - 1;
                float c0 = centers[2 * n], c1 = centers[2 * n + 1];
                float s0 = sharpness[2 * n], s1 = sharpness[2 * n + 1];
                Av[i][h] = BIAS_CONST - S_CONST * (s0 * c0 * c0 + s1 * c1 * c1);
                Bv[i][h] = S_CONST * 2.0f * s0 * c0;
                Cv[i][h] = S_CONST * 2.0f * s1 * c1;
                Dv[i][h] = -S_CONST * s0;
            }
        }
        main_loop<NPAIR, true>(B4, M4, quads, tid, Av, Bv, Cv, Dv, nullptr, acc);
    } else {
        // correctness fallback: two half-passes of 4 pairs keep VGPR <= iso path
        for (int pass = 0; pass < 2; ++pass) {
            v2f Av[NPAIR2], Bv[NPAIR2], Cv[NPAIR2], Dv[NPAIR2], Ev[NPAIR2];
#pragma unroll
            for (int i = 0; i < NPAIR2; ++i) {
#pragma unroll
                for (int h = 0; h < 2; ++h) {
                    int n = n0 + (pass * NPAIR2 + i) * 2 + h; if (n >= N) n = N - 1;
                    float c0 = centers[2 * n], c1 = centers[2 * n + 1];
                    float s0 = sharpness[2 * n], s1 = sharpness[2 * n + 1];
                    Av[i][h] = BIAS_CONST - S_CONST * (s0 * c0 * c0 + s1 * c1 * c1);
                    Bv[i][h] = S_CONST * 2.0f * s0 * c0;
                    Cv[i][h] = S_CONST * 2.0f * s1 * c1;
                    Dv[i][h] = -S_CONST * s0;
                    Ev[i][h] = -S_CONST * s1;
                }
            }
            main_loop<NPAIR2, false>(B4, M4, quads, tid, Av, Bv, Cv, Dv, Ev,
                                     acc + pass * NPAIR2);
        }
    }

    // Tail: P % 4 leftover points (not hit for P=8192), thread 0, scalar.
    if ((P & 3) && tid == 0) {
        const float* bb = batch + (size_t)b * P * 2;
        const float* mm = not_dummy + (size_t)b * P;
        for (int p = (quads << 2); p < P; ++p) {
            float x0 = bb[2 * p], x1 = bb[2 * p + 1], m = mm[p];
#pragma unroll
            for (int i = 0; i < NTILE; ++i) {
                int n = n0 + i; if (n >= N) n = N - 1;
                float c0 = centers[2 * n], c1 = centers[2 * n + 1];
                float s0 = sharpness[2 * n], s1 = sharpness[2 * n + 1];
                float d0 = x0 - c0, d1 = x1 - c1;
                float u = BIAS_CONST - S_CONST * (s0 * d0 * d0 + s1 * d1 * d1);
                acc[i >> 1][i & 1] += __int_as_float((int)u) * m;
            }
        }
    }

    // Wave-level butterfly reduction (64 lanes), then cross-wave via LDS.
    float red16[NTILE];
#pragma unroll
    for (int i = 0; i < NPAIR; ++i) { red16[2 * i] = acc[i].x; red16[2 * i + 1] = acc[i].y; }
#pragma unroll
    for (int i = 0; i < NTILE; ++i) {
        float v = red16[i];
#pragma unroll
        for (int off = 32; off >= 1; off >>= 1)
            v += __shfl_xor(v, off, 64);
        red16[i] = v;
    }

    __shared__ float red[THREADS / 64][NTILE];
    const int wave = tid >> 6;
    const int lane = tid & 63;
    if (lane == 0) {
#pragma unroll
        for (int i = 0; i < NTILE; ++i) red[wave][i] = red16[i];
    }
    __syncthreads();

    if (tid < NTILE && (n0 + tid) < N) {
        float v = 0.0f;
#pragma unroll
        for (int w = 0; w < THREADS / 64; ++w) v += red[w][tid];
        out[(size_t)b * N + n0 + tid] = v;
    }
}

extern "C" void kernel_launch(void* const* d_in, const int* in_sizes, int n_in,
                              void* d_out, int out_size, void* d_ws, size_t ws_size,
                              hipStream_t stream) {
    const float* batch     = (const float*)d_in[0];
    const float* not_dummy = (const float*)d_in[1];
    const float* centers   = (const float*)d_in[2];
    const float* sharp     = (const float*)d_in[3];
    float* out = (float*)d_out;

    const int N  = in_sizes[2] / 2;       // centers: [N,2]
    const int BP = in_sizes[1];           // not_dummy: [B,P]
    const int B  = out_size / N;          // out: [B,N]
    const int P  = BP / B;
    const int T  = (N + NTILE - 1) / NTILE;

    dim3 grid(T * B);
    slayer_exp_kernel<<<grid, THREADS, 0, stream>>>(batch, not_dummy, centers, sharp,
                                                    out, B, P, N, T);
}